// Round 1
// baseline (228.316 us; speedup 1.0000x reference)
//
#include <hip/hip_runtime.h>

// Fused: bilinear 2x upsample -> leaky_relu(0.01) -> bilinear 0.5x downsample
// (jax.image.resize, antialias=False, half-pixel centers).
// Collapses to a 3x3 clamped stencil per output pixel:
//   up taps per dim: even -> (0.25 prev, 0.75 cur), odd -> (0.75 cur, 0.25 next)
//   down = 2x2 average of leaky_relu'd up values.
// Shapes: x (16,128,128,128) fp32 NHWC, out same. C=128 contiguous -> float4/lane.

#define NEG_SLOPE 0.01f

__device__ __forceinline__ float lrelu(float v) {
    // where(v>=0, v, 0.01v) == max(v, 0.01v) for slope<1
    return fmaxf(v, NEG_SLOPE * v);
}

__device__ __forceinline__ float stencil(float a, float b, float c,
                                         float d, float e, float f,
                                         float g, float h, float i) {
    float up00 = 0.5625f * e + 0.1875f * (b + d) + 0.0625f * a;
    float up01 = 0.5625f * e + 0.1875f * (b + f) + 0.0625f * c;
    float up10 = 0.5625f * e + 0.1875f * (d + h) + 0.0625f * g;
    float up11 = 0.5625f * e + 0.1875f * (f + h) + 0.0625f * i;
    return 0.25f * (lrelu(up00) + lrelu(up01) + lrelu(up10) + lrelu(up11));
}

__global__ __launch_bounds__(256) void ActivationFilter_kernel(
        const float4* __restrict__ in, float4* __restrict__ out) {
    // idx over (B=16, H=128, W=128, C4=32) float4 groups
    const int idx = blockIdx.x * 256 + threadIdx.x;
    const int c4 = idx & 31;
    const int x  = (idx >> 5) & 127;
    const int y  = (idx >> 12) & 127;
    const int b  = idx >> 19;

    const int xm = max(x - 1, 0), xp = min(x + 1, 127);
    const int ym = max(y - 1, 0), yp = min(y + 1, 127);

    const int rb = b << 7;  // b*128
    // pixel (b,Y,X) base in float4 units: ((rb+Y)*128 + X)*32 + c4
#define LD(Y, X) in[((((rb + (Y)) << 7) + (X)) << 5) + c4]
    const float4 A = LD(ym, xm), B = LD(ym, x), C = LD(ym, xp);
    const float4 D = LD(y,  xm), E = LD(y,  x), F = LD(y,  xp);
    const float4 G = LD(yp, xm), H = LD(yp, x), I = LD(yp, xp);
#undef LD

    float4 o;
    o.x = stencil(A.x, B.x, C.x, D.x, E.x, F.x, G.x, H.x, I.x);
    o.y = stencil(A.y, B.y, C.y, D.y, E.y, F.y, G.y, H.y, I.y);
    o.z = stencil(A.z, B.z, C.z, D.z, E.z, F.z, G.z, H.z, I.z);
    o.w = stencil(A.w, B.w, C.w, D.w, E.w, F.w, G.w, H.w, I.w);

    out[idx] = o;
}

extern "C" void kernel_launch(void* const* d_in, const int* in_sizes, int n_in,
                              void* d_out, int out_size, void* d_ws, size_t ws_size,
                              hipStream_t stream) {
    const float4* in = (const float4*)d_in[0];
    float4* out = (float4*)d_out;
    // total float4 groups: 16*128*128*32 = 8388608 -> 32768 blocks of 256
    ActivationFilter_kernel<<<dim3(32768), dim3(256), 0, stream>>>(in, out);
}

// Round 3
// 226.748 us; speedup vs baseline: 1.0069x; 1.0069x over previous
//
#include <hip/hip_runtime.h>

// Fused bilinear-2x-up -> leaky_relu(0.01) -> bilinear-0.5x-down
// == 3x3 clamped-edge stencil per output pixel (derivation in R0):
//   up00 = .5625 e + .1875(b+d) + .0625 a   (etc. for the other 3 corners)
//   out  = 0.25 * sum(leaky_relu(up**))
//
// R3 structure: 2x2 output tile per thread. Load clamped 4x4 float4
// neighborhood (16 loads), emit 4 outputs -> 4 loads + 1 store per output
// (vs 9+1 in R1). Straight-line (no loop/rolling regs, which failed the
// post-timing tripwire in R2 for reasons never root-caused).
//
// Layout: (16,128,128,128) fp32 NHWC; C=128 -> 32 float4 groups, lane takes
// one c4 group: 32 consecutive lanes load 512 B contiguous per (row,col).

#define NEG_SLOPE 0.01f

__device__ __forceinline__ float lrelu(float v) {
    return fmaxf(v, NEG_SLOPE * v);  // slope < 1 => where(v>=0,v,s*v) == max
}

__device__ __forceinline__ float stencil(float a, float b, float c,
                                         float d, float e, float f,
                                         float g, float h, float i) {
    float up00 = 0.5625f * e + 0.1875f * (b + d) + 0.0625f * a;
    float up01 = 0.5625f * e + 0.1875f * (b + f) + 0.0625f * c;
    float up10 = 0.5625f * e + 0.1875f * (d + h) + 0.0625f * g;
    float up11 = 0.5625f * e + 0.1875f * (f + h) + 0.0625f * i;
    return 0.25f * (lrelu(up00) + lrelu(up01) + lrelu(up10) + lrelu(up11));
}

__device__ __forceinline__ float4 stencil4(const float4& a, const float4& b, const float4& c,
                                           const float4& d, const float4& e, const float4& f,
                                           const float4& g, const float4& h, const float4& i) {
    float4 o;
    o.x = stencil(a.x, b.x, c.x, d.x, e.x, f.x, g.x, h.x, i.x);
    o.y = stencil(a.y, b.y, c.y, d.y, e.y, f.y, g.y, h.y, i.y);
    o.z = stencil(a.z, b.z, c.z, d.z, e.z, f.z, g.z, h.z, i.z);
    o.w = stencil(a.w, b.w, c.w, d.w, e.w, f.w, g.w, h.w, i.w);
    return o;
}

__global__ __launch_bounds__(256) void ActivationFilter_kernel(
        const float4* __restrict__ in, float4* __restrict__ out) {
    // thread -> (b, y-pair, x-pair, c4): 16 * 64 * 64 * 32 = 2,097,152
    const int t  = blockIdx.x * 256 + threadIdx.x;
    const int c4 = t & 31;
    const int px = (t >> 5) & 63;
    const int py = (t >> 11) & 63;
    const int b  = t >> 17;

    const int x0 = px << 1, y0 = py << 1;
    const int xm = max(x0 - 1, 0), x3 = min(x0 + 2, 127);
    const int ym = max(y0 - 1, 0), y3 = min(y0 + 2, 127);

    const int rb = b << 7;  // b*128
    // float4-unit address of (b, Y, X, c4)
#define ADDR(Y, X) (((((rb + (Y)) << 7) + (X)) << 5) + c4)

    // 4x4 clamped neighborhood: rows {ym, y0, y0+1, y3} x cols {xm, x0, x0+1, x3}
    const float4 v00 = in[ADDR(ym,   xm)], v01 = in[ADDR(ym,   x0)],
                 v02 = in[ADDR(ym,   x0+1)], v03 = in[ADDR(ym,   x3)];
    const float4 v10 = in[ADDR(y0,   xm)], v11 = in[ADDR(y0,   x0)],
                 v12 = in[ADDR(y0,   x0+1)], v13 = in[ADDR(y0,   x3)];
    const float4 v20 = in[ADDR(y0+1, xm)], v21 = in[ADDR(y0+1, x0)],
                 v22 = in[ADDR(y0+1, x0+1)], v23 = in[ADDR(y0+1, x3)];
    const float4 v30 = in[ADDR(y3,   xm)], v31 = in[ADDR(y3,   x0)],
                 v32 = in[ADDR(y3,   x0+1)], v33 = in[ADDR(y3,   x3)];

    out[ADDR(y0,   x0  )] = stencil4(v00, v01, v02, v10, v11, v12, v20, v21, v22);
    out[ADDR(y0,   x0+1)] = stencil4(v01, v02, v03, v11, v12, v13, v21, v22, v23);
    out[ADDR(y0+1, x0  )] = stencil4(v10, v11, v12, v20, v21, v22, v30, v31, v32);
    out[ADDR(y0+1, x0+1)] = stencil4(v11, v12, v13, v21, v22, v23, v31, v32, v33);
#undef ADDR
}

extern "C" void kernel_launch(void* const* d_in, const int* in_sizes, int n_in,
                              void* d_out, int out_size, void* d_ws, size_t ws_size,
                              hipStream_t stream) {
    const float4* in = (const float4*)d_in[0];
    float4* out = (float4*)d_out;
    // 2,097,152 threads -> 8192 blocks of 256
    ActivationFilter_kernel<<<dim3(8192), dim3(256), 0, stream>>>(in, out);
}